// Round 4
// baseline (3100.234 us; speedup 1.0000x reference)
//
#include <hip/hip_runtime.h>
#include <math.h>

#define NB   8
#define NC   192
#define NPIX 3136
#define NBLK 49            // 3136/64 j-tiles (and i-tiles for knn)
#define SPLIT 8            // j-range splits per i-tile
#define GRID_LL (NB*98)    // 784: M-tile 32
#define GRID_KNN (NB*SPLIT*NBLK)   // 3136
#define GRID_MSG (NB*196)  // 1568: 16 rows per block
#define FINF 3.4e38f

__device__ __forceinline__ float gelu_f(float x){
    float u = 0.7978845608028654f * (x + 0.044715f * x * x * x);
    return 0.5f * x * (1.0f + tanhf(u));
}

// insert candidate into sorted-ascending (d, id) 9-list; lex tie-break on lower idx
__device__ __forceinline__ void ins9(float (&d)[9], int (&id)[9], float nd, int ni){
    bool better = (nd < d[8]) || (nd == d[8] && ni < id[8]);
    if (better){
        d[8] = nd; id[8] = ni;
        #pragma unroll
        for (int s = 8; s > 0; --s){
            bool sw = (d[s] < d[s-1]) || (d[s] == d[s-1] && id[s] < id[s-1]);
            if (sw){
                float td = d[s]; d[s] = d[s-1]; d[s-1] = td;
                int   ti = id[s]; id[s] = id[s-1]; id[s-1] = ti;
            }
        }
    }
}

// ---------------------------------------------------------------------------
// Fused GEMM + lorentz_linear. Tile 32 rows x 192 cols, 256 thr:
// tx (0..15) covers 12 cols each, ty (0..15) covers 2 rows each.
// ---------------------------------------------------------------------------
template<int K, bool IN_X, bool ADD_X, bool ADD_RM, bool OUT_T>
__global__ __launch_bounds__(256, 4) void ll_kernel(
    const float* __restrict__ Ain, int in_stride,
    const float* __restrict__ Wt,     // [NC, K] row-major
    const float* __restrict__ bias,   // [NC]
    const float* __restrict__ sptr,   // scalar log_scale
    const float* __restrict__ Xres,   // x (B,C,N) residual, if ADD_X
    const float* __restrict__ Rrm, int r_stride,  // row-major residual, if ADD_RM
    float* __restrict__ Out, int out_stride)
{
    __shared__ float lA[32*36];    // [kk][mm], pad 36
    __shared__ float lW[32*196];   // [kk][nn], pad 196

    const int tid = threadIdx.x;
    const int tx = tid & 15, ty = tid >> 4;
    const int bid = blockIdx.x;
    const int b  = bid / 98;
    const int n0 = (bid % 98) * 32;
    const int row0 = b * NPIX + n0;

    float acc[2][12];
    #pragma unroll
    for (int mi = 0; mi < 2; ++mi)
        #pragma unroll
        for (int j = 0; j < 12; ++j) acc[mi][j] = 0.f;

    for (int kt = 0; kt < K/32; ++kt){
        // ---- stage A (gelu applied here): 32k x 32m ----
        if (IN_X){
            int kk = tid >> 3;
            int m4 = (tid & 7) * 4;
            float4 v = *(const float4*)&Ain[(size_t)(b*NC + kt*32 + kk)*NPIX + n0 + m4];
            v.x = gelu_f(v.x); v.y = gelu_f(v.y); v.z = gelu_f(v.z); v.w = gelu_f(v.w);
            *(float4*)&lA[kk*36 + m4] = v;
        } else {
            int mm = tid >> 3;
            int k4 = (tid & 7) * 4;
            float4 v = *(const float4*)&Ain[(size_t)(row0 + mm)*in_stride + kt*32 + k4];
            v.x = gelu_f(v.x); v.y = gelu_f(v.y); v.z = gelu_f(v.z); v.w = gelu_f(v.w);
            lA[(k4+0)*36 + mm] = v.x; lA[(k4+1)*36 + mm] = v.y;
            lA[(k4+2)*36 + mm] = v.z; lA[(k4+3)*36 + mm] = v.w;
        }
        // ---- stage W (transposed): 32k x 192n ----
        #pragma unroll
        for (int r = 0; r < 6; ++r){
            int e  = tid + r*256;
            int nn = e >> 3;
            int k4 = (e & 7) * 4;
            float4 v = *(const float4*)&Wt[nn*K + kt*32 + k4];
            lW[(k4+0)*196 + nn] = v.x; lW[(k4+1)*196 + nn] = v.y;
            lW[(k4+2)*196 + nn] = v.z; lW[(k4+3)*196 + nn] = v.w;
        }
        __syncthreads();
        #pragma unroll
        for (int kk = 0; kk < 32; ++kk){
            float2 a2 = *(const float2*)&lA[kk*36 + ty*2];
            float4 w0 = *(const float4*)&lW[kk*196 + tx*12];
            float4 w1 = *(const float4*)&lW[kk*196 + tx*12 + 4];
            float4 w2 = *(const float4*)&lW[kk*196 + tx*12 + 8];
            float aw[2]  = {a2.x, a2.y};
            float wv[12] = {w0.x,w0.y,w0.z,w0.w, w1.x,w1.y,w1.z,w1.w, w2.x,w2.y,w2.z,w2.w};
            #pragma unroll
            for (int mi = 0; mi < 2; ++mi)
                #pragma unroll
                for (int j = 0; j < 12; ++j)
                    acc[mi][j] = fmaf(aw[mi], wv[j], acc[mi][j]);
        }
        __syncthreads();
    }

    // ---- lorentz epilogue ----
    const int lane = tid & 63;
    float es = expf(sptr[0]);
    float bv[12];
    #pragma unroll
    for (int q = 0; q < 3; ++q){
        float4 t4 = *(const float4*)&bias[tx*12 + q*4];
        bv[q*4+0] = t4.x; bv[q*4+1] = t4.y; bv[q*4+2] = t4.z; bv[q*4+3] = t4.w;
    }
    #pragma unroll
    for (int mi = 0; mi < 2; ++mi){
        float part = 0.f;
        #pragma unroll
        for (int j = 0; j < 12; ++j){
            float y = acc[mi][j] + bv[j];
            acc[mi][j] = y;
            if (!(tx == 0 && j == 0)) part += y * y;   // exclude global col 0
        }
        #pragma unroll
        for (int m = 1; m < 16; m <<= 1) part += __shfl_xor(part, m, 64);
        float y0   = __shfl(acc[mi][0], lane & 48, 64);   // col-0 value of this row
        float tval = es / (1.f + expf(-y0)) + 1.1f;
        float denom = fmaxf(part, 1e-8f);
        float sca  = (tval*tval - 1.f) / denom;
        float sqs  = sqrtf(sca);
        #pragma unroll
        for (int j = 0; j < 12; ++j){
            float o = acc[mi][j] * sqs;
            if (tx == 0 && j == 0) o = tval;
            acc[mi][j] = o;
        }
    }
    if (ADD_X){
        #pragma unroll
        for (int j = 0; j < 12; ++j){
            int c = tx*12 + j;
            float2 xv = *(const float2*)&Xres[(size_t)(b*NC + c)*NPIX + n0 + ty*2];
            acc[0][j] += xv.x; acc[1][j] += xv.y;
        }
    }
    if (ADD_RM){
        #pragma unroll
        for (int mi = 0; mi < 2; ++mi){
            #pragma unroll
            for (int q = 0; q < 3; ++q){
                float4 rv = *(const float4*)&Rrm[(size_t)(row0 + ty*2 + mi)*r_stride + tx*12 + q*4];
                acc[mi][q*4+0] += rv.x; acc[mi][q*4+1] += rv.y;
                acc[mi][q*4+2] += rv.z; acc[mi][q*4+3] += rv.w;
            }
        }
    }
    if (OUT_T){
        #pragma unroll
        for (int j = 0; j < 12; ++j){
            int c = tx*12 + j;
            *(float2*)&Out[(size_t)(b*NC + c)*NPIX + n0 + ty*2] = make_float2(acc[0][j], acc[1][j]);
        }
    } else {
        #pragma unroll
        for (int mi = 0; mi < 2; ++mi){
            #pragma unroll
            for (int q = 0; q < 3; ++q){
                float4 o = make_float4(acc[mi][q*4+0], acc[mi][q*4+1], acc[mi][q*4+2], acc[mi][q*4+3]);
                *(float4*)&Out[(size_t)(row0 + ty*2 + mi)*out_stride + tx*12 + q*4] = o;
            }
        }
    }
}

// ---------------------------------------------------------------------------
// Row squared-norms of xn1 (stored in H cols [0,192), stride 384)
// ---------------------------------------------------------------------------
__global__ __launch_bounds__(256) void sq_kernel(const float* __restrict__ H, float* __restrict__ SQ){
    int tid = threadIdx.x;
    int row = blockIdx.x * 64 + (tid >> 2);
    const float* p = H + (size_t)row*384 + (tid & 3)*48;
    float s = 0.f;
    #pragma unroll
    for (int q = 0; q < 12; ++q){
        float4 v = *(const float4*)&p[q*4];
        s = fmaf(v.x, v.x, fmaf(v.y, v.y, fmaf(v.z, v.z, fmaf(v.w, v.w, s))));
    }
    s += __shfl_xor(s, 1, 64);
    s += __shfl_xor(s, 2, 64);
    if ((tid & 3) == 0) SQ[row] = s;
}

// XOR-swizzled LDS float index: row-stride 64, quad permuted by (row&15)
__device__ __forceinline__ int swz(int r, int cq){
    return r*64 + ((cq ^ (r & 15)) << 2);
}

// ---------------------------------------------------------------------------
// Partial kNN(top-9). Block = 64 i-rows x (subset of j-tiles). 256 thr =
// 32 ty (2 i-rows: ty, ty+32) x 8 tx (8 j: tx+8*jj). c chunked x64.
// Writes per-row top-9 (d,idx) partials; merged by merge_msg_kernel.
// ---------------------------------------------------------------------------
__global__ __launch_bounds__(256, 4) void knn_kernel(
    const float* __restrict__ H, const float* __restrict__ SQ,
    float* __restrict__ PD, int* __restrict__ PI)
{
    __shared__ float lXi[4096];
    __shared__ float lXj[4096];
    __shared__ float lSq[64];

    const int tid = threadIdx.x;
    const int tx = tid & 7, ty = tid >> 3;
    const int bid = blockIdx.x;             // ((b*SPLIT + sp)*NBLK + itile)
    const int itile = bid % NBLK;
    const int t2  = bid / NBLK;
    const int sp  = t2 % SPLIT;
    const int b   = t2 / SPLIT;
    const int i0  = itile * 64;
    const int base = b * NPIX;
    const int jt0 = (sp * NBLK) / SPLIT;
    const int jt1 = ((sp + 1) * NBLK) / SPLIT;

    float topd[2][9]; int topi[2][9];
    #pragma unroll
    for (int mi = 0; mi < 2; ++mi)
        #pragma unroll
        for (int e = 0; e < 9; ++e){ topd[mi][e] = FINF; topi[mi][e] = 0x7FFFFFFF; }

    for (int jt = jt0; jt < jt1; ++jt){
        int j0 = jt * 64;
        float dac[2][8];
        #pragma unroll
        for (int mi = 0; mi < 2; ++mi)
            #pragma unroll
            for (int jj = 0; jj < 8; ++jj) dac[mi][jj] = 0.f;

        for (int ch = 0; ch < 3; ++ch){
            __syncthreads();
            #pragma unroll
            for (int r = 0; r < 4; ++r){
                int e  = tid + r*256;          // 1024 float4 = 64 rows x 16 quads
                int rw = e >> 4;
                int q  = e & 15;
                float4 vi = *(const float4*)&H[(size_t)(base + i0 + rw)*384 + ch*64 + q*4];
                *(float4*)&lXi[swz(rw, q)] = vi;
                float4 vj = *(const float4*)&H[(size_t)(base + j0 + rw)*384 + ch*64 + q*4];
                *(float4*)&lXj[swz(rw, q)] = vj;
            }
            if (ch == 0 && tid < 16){
                float4 sv = *(const float4*)&SQ[base + j0 + tid*4];
                *(float4*)&lSq[tid*4] = sv;
            }
            __syncthreads();
            #pragma unroll
            for (int cq = 0; cq < 16; ++cq){
                float4 a0 = *(const float4*)&lXi[swz(ty,      cq)];
                float4 a1 = *(const float4*)&lXi[swz(ty + 32, cq)];
                #pragma unroll
                for (int jj = 0; jj < 8; ++jj){
                    float4 w = *(const float4*)&lXj[swz(tx + 8*jj, cq)];
                    dac[0][jj] = fmaf(a0.x, w.x, fmaf(a0.y, w.y, fmaf(a0.z, w.z, fmaf(a0.w, w.w, dac[0][jj]))));
                    dac[1][jj] = fmaf(a1.x, w.x, fmaf(a1.y, w.y, fmaf(a1.z, w.z, fmaf(a1.w, w.w, dac[1][jj]))));
                }
            }
        }
        #pragma unroll
        for (int jj = 0; jj < 8; ++jj){
            int j = j0 + tx + 8*jj;
            float sqj = lSq[tx + 8*jj];
            #pragma unroll
            for (int mi = 0; mi < 2; ++mi){
                float d = fmaf(-2.f, dac[mi][jj], sqj);
                ins9(topd[mi], topi[mi], d, j);
            }
        }
    }

    // ---- merge 8 tx-stripes per row; rows 0-31 (h=0) then 32-63 (h=1) ----
    float* smd = lXi;
    int*   smi = (int*)lXj;
    for (int h = 0; h < 2; ++h){
        __syncthreads();
        #pragma unroll
        for (int e = 0; e < 9; ++e){
            smd[(ty*8 + tx)*9 + e] = topd[h][e];
            smi[(ty*8 + tx)*9 + e] = topi[h][e];
        }
        __syncthreads();
        if (tid < 32){
            float md[9]; int mid[9];
            #pragma unroll
            for (int e = 0; e < 9; ++e){ md[e] = FINF; mid[e] = 0x7FFFFFFF; }
            for (int t = 0; t < 8; ++t){
                #pragma unroll
                for (int e = 0; e < 9; ++e)
                    ins9(md, mid, smd[(tid*8 + t)*9 + e], smi[(tid*8 + t)*9 + e]);
            }
            size_t po = ((size_t)bid*64 + h*32 + tid)*9;
            #pragma unroll
            for (int e = 0; e < 9; ++e){ PD[po + e] = md[e]; PI[po + e] = mid[e]; }
        }
    }
}

// ---------------------------------------------------------------------------
// Merge SPLIT partial top-9 lists per row, then gather max-message.
// Block = 16 rows; msg written to H cols [192,384).
// ---------------------------------------------------------------------------
__global__ __launch_bounds__(256) void merge_msg_kernel(
    const float* __restrict__ H, const float* __restrict__ PD, const int* __restrict__ PI,
    float* __restrict__ Hout)
{
    __shared__ int fidx[16*9];
    const int tid = threadIdx.x;
    const int bid = blockIdx.x;
    const int b  = bid / 196;
    const int i0 = (bid % 196) * 16;
    const int base = b * NPIX;

    if (tid < 16){
        int i = i0 + tid;
        int itile = i >> 6, rl = i & 63;
        float md[9]; int mid[9];
        #pragma unroll
        for (int e = 0; e < 9; ++e){ md[e] = FINF; mid[e] = 0x7FFFFFFF; }
        for (int sp = 0; sp < SPLIT; ++sp){
            size_t po = ((size_t)(((b*SPLIT + sp)*NBLK) + itile)*64 + rl)*9;
            #pragma unroll
            for (int e = 0; e < 9; ++e) ins9(md, mid, PD[po + e], PI[po + e]);
        }
        #pragma unroll
        for (int e = 0; e < 9; ++e) fidx[tid*9 + e] = mid[e];
    }
    __syncthreads();

    int rl = tid >> 4, part = tid & 15;       // 16 rows x 16 col-parts (12 cols each)
    int i = i0 + rl;
    int nbr[9];
    #pragma unroll
    for (int e = 0; e < 9; ++e) nbr[e] = fidx[rl*9 + e];
    const float* pi = H + (size_t)(base + i)*384 + part*12;
    float* po = Hout + (size_t)(base + i)*384 + 192 + part*12;
    #pragma unroll
    for (int q = 0; q < 3; ++q){
        float4 mv = make_float4(-FINF, -FINF, -FINF, -FINF);
        #pragma unroll
        for (int e = 0; e < 9; ++e){
            float4 v = *(const float4*)&H[(size_t)(base + nbr[e])*384 + part*12 + q*4];
            mv.x = fmaxf(mv.x, v.x); mv.y = fmaxf(mv.y, v.y);
            mv.z = fmaxf(mv.z, v.z); mv.w = fmaxf(mv.w, v.w);
        }
        float4 xi = *(const float4*)&pi[q*4];
        *(float4*)&po[q*4] = make_float4(mv.x - xi.x, mv.y - xi.y, mv.z - xi.z, mv.w - xi.w);
    }
}

extern "C" void kernel_launch(void* const* d_in, const int* in_sizes, int n_in,
                              void* d_out, int out_size, void* d_ws, size_t ws_size,
                              hipStream_t stream)
{
    const float* x  = (const float*)d_in[0];
    const float* W1 = (const float*)d_in[1];
    const float* b1 = (const float*)d_in[2];
    const float* s1 = (const float*)d_in[3];
    const float* W2 = (const float*)d_in[4];
    const float* b2 = (const float*)d_in[5];
    const float* s2 = (const float*)d_in[6];
    const float* Wg = (const float*)d_in[7];
    const float* bg = (const float*)d_in[8];
    const float* sg = (const float*)d_in[9];
    const float* W3 = (const float*)d_in[10];
    const float* b3 = (const float*)d_in[11];
    const float* s3 = (const float*)d_in[12];
    const float* W4 = (const float*)d_in[13];
    const float* b4 = (const float*)d_in[14];
    const float* s4 = (const float*)d_in[15];

    float* H  = (float*)d_ws;                       // [25088][384]: xn1 | msg
    float* T1 = H  + (size_t)25088*384;             // LL1 out (dead before partials reuse); later LL3 out
    float* X2 = T1 + (size_t)25088*192;             // graph-conv out (xn2)
    float* SQ = X2 + (size_t)25088*192;             // row sq-norms
    float* PD = T1;                                 // partial dists  (GRID_KNN*64*9 = 1.81M floats)
    int*   PI = (int*)(T1 + (size_t)GRID_KNN*64*9); // partial indices (1.81M ints)
    float* out = (float*)d_out;

    // ffn_lorentz #1
    ll_kernel<192, true , false, false, false><<<GRID_LL, 256, 0, stream>>>(x, 0,   W1, b1, s1, nullptr, nullptr, 0, T1, 192);
    ll_kernel<192, false, true , false, false><<<GRID_LL, 256, 0, stream>>>(T1, 192, W2, b2, s2, x,      nullptr, 0, H, 384);
    // graph conv
    sq_kernel<<<NB*NBLK, 256, 0, stream>>>(H, SQ);
    knn_kernel<<<GRID_KNN, 256, 0, stream>>>(H, SQ, PD, PI);
    merge_msg_kernel<<<GRID_MSG, 256, 0, stream>>>(H, PD, PI, H);
    ll_kernel<384, false, false, false, false><<<GRID_LL, 256, 0, stream>>>(H, 384,  Wg, bg, sg, nullptr, nullptr, 0, X2, 192);
    // ffn_lorentz #2 + final shortcut, transposed store
    ll_kernel<192, false, false, false, false><<<GRID_LL, 256, 0, stream>>>(X2, 192, W3, b3, s3, nullptr, nullptr, 0, T1, 192);
    ll_kernel<192, false, true , true , true ><<<GRID_LL, 256, 0, stream>>>(T1, 192, W4, b4, s4, x,      X2, 192, out, 0);
}

// Round 5
// 1612.406 us; speedup vs baseline: 1.9227x; 1.9227x over previous
//
#include <hip/hip_runtime.h>
#include <math.h>

#define NB   8
#define NC   192
#define NPIX 3136
#define NBLK 49            // 3136/64 j-tiles (and i-tiles for knn)
#define SPLIT 8            // j-range splits per i-tile
#define GRID_LL (NB*98)    // 784: M-tile 32
#define GRID_KNN (NB*SPLIT*NBLK)   // 3136
#define GRID_MSG (NB*196)  // 1568: 16 rows per block
#define FINF 3.4e38f

__device__ __forceinline__ float gelu_f(float x){
    float u = 0.7978845608028654f * (x + 0.044715f * x * x * x);
    return 0.5f * x * (1.0f + tanhf(u));
}

// insert candidate into sorted-ascending (d, id) 9-list; lex tie-break on lower idx
__device__ __forceinline__ void ins9(float (&d)[9], int (&id)[9], float nd, int ni){
    bool better = (nd < d[8]) || (nd == d[8] && ni < id[8]);
    if (better){
        d[8] = nd; id[8] = ni;
        #pragma unroll
        for (int s = 8; s > 0; --s){
            bool sw = (d[s] < d[s-1]) || (d[s] == d[s-1] && id[s] < id[s-1]);
            if (sw){
                float td = d[s]; d[s] = d[s-1]; d[s-1] = td;
                int   ti = id[s]; id[s] = id[s-1]; id[s-1] = ti;
            }
        }
    }
}

// ---------------------------------------------------------------------------
// Fused GEMM + lorentz_linear. Tile 32 rows x 192 cols, 256 thr:
// tx (0..15) covers 12 cols each, ty (0..15) covers 2 rows each.
// ---------------------------------------------------------------------------
template<int K, bool IN_X, bool ADD_X, bool ADD_RM, bool OUT_T>
__global__ __launch_bounds__(256, 4) void ll_kernel(
    const float* __restrict__ Ain, int in_stride,
    const float* __restrict__ Wt,     // [NC, K] row-major
    const float* __restrict__ bias,   // [NC]
    const float* __restrict__ sptr,   // scalar log_scale
    const float* __restrict__ Xres,   // x (B,C,N) residual, if ADD_X
    const float* __restrict__ Rrm, int r_stride,  // row-major residual, if ADD_RM
    float* __restrict__ Out, int out_stride)
{
    __shared__ float lA[32*36];    // [kk][mm], pad 36
    __shared__ float lW[32*196];   // [kk][nn], pad 196

    const int tid = threadIdx.x;
    const int tx = tid & 15, ty = tid >> 4;
    const int bid = blockIdx.x;
    const int b  = bid / 98;
    const int n0 = (bid % 98) * 32;
    const int row0 = b * NPIX + n0;

    float acc[2][12];
    #pragma unroll
    for (int mi = 0; mi < 2; ++mi)
        #pragma unroll
        for (int j = 0; j < 12; ++j) acc[mi][j] = 0.f;

    for (int kt = 0; kt < K/32; ++kt){
        // ---- stage A (gelu applied here): 32k x 32m ----
        if (IN_X){
            int kk = tid >> 3;
            int m4 = (tid & 7) * 4;
            float4 v = *(const float4*)&Ain[(size_t)(b*NC + kt*32 + kk)*NPIX + n0 + m4];
            v.x = gelu_f(v.x); v.y = gelu_f(v.y); v.z = gelu_f(v.z); v.w = gelu_f(v.w);
            *(float4*)&lA[kk*36 + m4] = v;
        } else {
            int mm = tid >> 3;
            int k4 = (tid & 7) * 4;
            float4 v = *(const float4*)&Ain[(size_t)(row0 + mm)*in_stride + kt*32 + k4];
            v.x = gelu_f(v.x); v.y = gelu_f(v.y); v.z = gelu_f(v.z); v.w = gelu_f(v.w);
            lA[(k4+0)*36 + mm] = v.x; lA[(k4+1)*36 + mm] = v.y;
            lA[(k4+2)*36 + mm] = v.z; lA[(k4+3)*36 + mm] = v.w;
        }
        // ---- stage W (transposed): 32k x 192n ----
        #pragma unroll
        for (int r = 0; r < 6; ++r){
            int e  = tid + r*256;
            int nn = e >> 3;
            int k4 = (e & 7) * 4;
            float4 v = *(const float4*)&Wt[nn*K + kt*32 + k4];
            lW[(k4+0)*196 + nn] = v.x; lW[(k4+1)*196 + nn] = v.y;
            lW[(k4+2)*196 + nn] = v.z; lW[(k4+3)*196 + nn] = v.w;
        }
        __syncthreads();
        #pragma unroll
        for (int kk = 0; kk < 32; ++kk){
            float2 a2 = *(const float2*)&lA[kk*36 + ty*2];
            float4 w0 = *(const float4*)&lW[kk*196 + tx*12];
            float4 w1 = *(const float4*)&lW[kk*196 + tx*12 + 4];
            float4 w2 = *(const float4*)&lW[kk*196 + tx*12 + 8];
            float aw[2]  = {a2.x, a2.y};
            float wv[12] = {w0.x,w0.y,w0.z,w0.w, w1.x,w1.y,w1.z,w1.w, w2.x,w2.y,w2.z,w2.w};
            #pragma unroll
            for (int mi = 0; mi < 2; ++mi)
                #pragma unroll
                for (int j = 0; j < 12; ++j)
                    acc[mi][j] = fmaf(aw[mi], wv[j], acc[mi][j]);
        }
        __syncthreads();
    }

    // ---- lorentz epilogue ----
    const int lane = tid & 63;
    float es = expf(sptr[0]);
    float bv[12];
    #pragma unroll
    for (int q = 0; q < 3; ++q){
        float4 t4 = *(const float4*)&bias[tx*12 + q*4];
        bv[q*4+0] = t4.x; bv[q*4+1] = t4.y; bv[q*4+2] = t4.z; bv[q*4+3] = t4.w;
    }
    #pragma unroll
    for (int mi = 0; mi < 2; ++mi){
        float part = 0.f;
        #pragma unroll
        for (int j = 0; j < 12; ++j){
            float y = acc[mi][j] + bv[j];
            acc[mi][j] = y;
            if (!(tx == 0 && j == 0)) part += y * y;   // exclude global col 0
        }
        #pragma unroll
        for (int m = 1; m < 16; m <<= 1) part += __shfl_xor(part, m, 64);
        float y0   = __shfl(acc[mi][0], lane & 48, 64);   // col-0 value of this row
        float tval = es / (1.f + expf(-y0)) + 1.1f;
        float denom = fmaxf(part, 1e-8f);
        float sca  = (tval*tval - 1.f) / denom;
        float sqs  = sqrtf(sca);
        #pragma unroll
        for (int j = 0; j < 12; ++j){
            float o = acc[mi][j] * sqs;
            if (tx == 0 && j == 0) o = tval;
            acc[mi][j] = o;
        }
    }
    if (ADD_X){
        #pragma unroll
        for (int j = 0; j < 12; ++j){
            int c = tx*12 + j;
            float2 xv = *(const float2*)&Xres[(size_t)(b*NC + c)*NPIX + n0 + ty*2];
            acc[0][j] += xv.x; acc[1][j] += xv.y;
        }
    }
    if (ADD_RM){
        #pragma unroll
        for (int mi = 0; mi < 2; ++mi){
            #pragma unroll
            for (int q = 0; q < 3; ++q){
                float4 rv = *(const float4*)&Rrm[(size_t)(row0 + ty*2 + mi)*r_stride + tx*12 + q*4];
                acc[mi][q*4+0] += rv.x; acc[mi][q*4+1] += rv.y;
                acc[mi][q*4+2] += rv.z; acc[mi][q*4+3] += rv.w;
            }
        }
    }
    if (OUT_T){
        #pragma unroll
        for (int j = 0; j < 12; ++j){
            int c = tx*12 + j;
            *(float2*)&Out[(size_t)(b*NC + c)*NPIX + n0 + ty*2] = make_float2(acc[0][j], acc[1][j]);
        }
    } else {
        #pragma unroll
        for (int mi = 0; mi < 2; ++mi){
            #pragma unroll
            for (int q = 0; q < 3; ++q){
                float4 o = make_float4(acc[mi][q*4+0], acc[mi][q*4+1], acc[mi][q*4+2], acc[mi][q*4+3]);
                *(float4*)&Out[(size_t)(row0 + ty*2 + mi)*out_stride + tx*12 + q*4] = o;
            }
        }
    }
}

// ---------------------------------------------------------------------------
// Row squared-norms of xn1 (stored in H cols [0,192), stride 384)
// ---------------------------------------------------------------------------
__global__ __launch_bounds__(256) void sq_kernel(const float* __restrict__ H, float* __restrict__ SQ){
    int tid = threadIdx.x;
    int row = blockIdx.x * 64 + (tid >> 2);
    const float* p = H + (size_t)row*384 + (tid & 3)*48;
    float s = 0.f;
    #pragma unroll
    for (int q = 0; q < 12; ++q){
        float4 v = *(const float4*)&p[q*4];
        s = fmaf(v.x, v.x, fmaf(v.y, v.y, fmaf(v.z, v.z, fmaf(v.w, v.w, s))));
    }
    s += __shfl_xor(s, 1, 64);
    s += __shfl_xor(s, 2, 64);
    if ((tid & 3) == 0) SQ[row] = s;
}

// XOR-swizzled LDS float index: row-stride 64, quad permuted by (row&15)
__device__ __forceinline__ int swz(int r, int cq){
    return r*64 + ((cq ^ (r & 15)) << 2);
}

// ---------------------------------------------------------------------------
// Partial kNN(top-9). Block = 64 i-rows x (subset of j-tiles). 256 thr =
// 32 ty (2 i-rows: ty, ty+32) x 8 tx (8 j: tx+8*jj). c chunked x64.
// bid = (sp*NBLK + itile)*8 + b  -> XCD round-robin keeps one batch per XCD.
// Writes per-row top-9 (d,idx) partials; merged by merge_msg_kernel.
// ---------------------------------------------------------------------------
__global__ __launch_bounds__(256, 4) void knn_kernel(
    const float* __restrict__ H, const float* __restrict__ SQ,
    float* __restrict__ PD, int* __restrict__ PI)
{
    __shared__ float lXi[4096];
    __shared__ float lXj[4096];
    __shared__ float lSq[64];

    const int tid = threadIdx.x;
    const int tx = tid & 7, ty = tid >> 3;
    const int bid = blockIdx.x;
    const int b   = bid & 7;                // XCD-aligned batch
    const int t2  = bid >> 3;               // sp*NBLK + itile
    const int itile = t2 % NBLK;
    const int sp  = t2 / NBLK;
    const int i0  = itile * 64;
    const int base = b * NPIX;
    const int jt0 = (sp * NBLK) / SPLIT;
    const int jt1 = ((sp + 1) * NBLK) / SPLIT;

    float topd0[9], topd1[9]; int topi0[9], topi1[9];
    #pragma unroll
    for (int e = 0; e < 9; ++e){
        topd0[e] = FINF; topi0[e] = 0x7FFFFFFF;
        topd1[e] = FINF; topi1[e] = 0x7FFFFFFF;
    }

    for (int jt = jt0; jt < jt1; ++jt){
        int j0 = jt * 64;
        float dac[2][8];
        #pragma unroll
        for (int mi = 0; mi < 2; ++mi)
            #pragma unroll
            for (int jj = 0; jj < 8; ++jj) dac[mi][jj] = 0.f;

        for (int ch = 0; ch < 3; ++ch){
            __syncthreads();
            #pragma unroll
            for (int r = 0; r < 4; ++r){
                int e  = tid + r*256;          // 1024 float4 = 64 rows x 16 quads
                int rw = e >> 4;
                int q  = e & 15;
                float4 vi = *(const float4*)&H[(size_t)(base + i0 + rw)*384 + ch*64 + q*4];
                *(float4*)&lXi[swz(rw, q)] = vi;
                float4 vj = *(const float4*)&H[(size_t)(base + j0 + rw)*384 + ch*64 + q*4];
                *(float4*)&lXj[swz(rw, q)] = vj;
            }
            if (ch == 0 && tid < 16){
                float4 sv = *(const float4*)&SQ[base + j0 + tid*4];
                *(float4*)&lSq[tid*4] = sv;
            }
            __syncthreads();
            #pragma unroll
            for (int cq = 0; cq < 16; ++cq){
                float4 a0 = *(const float4*)&lXi[swz(ty,      cq)];
                float4 a1 = *(const float4*)&lXi[swz(ty + 32, cq)];
                #pragma unroll
                for (int jj = 0; jj < 8; ++jj){
                    float4 w = *(const float4*)&lXj[swz(tx + 8*jj, cq)];
                    dac[0][jj] = fmaf(a0.x, w.x, fmaf(a0.y, w.y, fmaf(a0.z, w.z, fmaf(a0.w, w.w, dac[0][jj]))));
                    dac[1][jj] = fmaf(a1.x, w.x, fmaf(a1.y, w.y, fmaf(a1.z, w.z, fmaf(a1.w, w.w, dac[1][jj]))));
                }
            }
        }
        #pragma unroll
        for (int jj = 0; jj < 8; ++jj){
            int j = j0 + tx + 8*jj;
            float sqj = lSq[tx + 8*jj];
            float d0 = fmaf(-2.f, dac[0][jj], sqj);
            ins9(topd0, topi0, d0, j);
            float d1 = fmaf(-2.f, dac[1][jj], sqj);
            ins9(topd1, topi1, d1, j);
        }
    }

    // ---- merge 8 tx-stripes per row; statically unrolled halves ----
    float* smd = lXi;
    int*   smi = (int*)lXj;

    // rows 0..31 (i = i0 + ty)
    __syncthreads();
    #pragma unroll
    for (int e = 0; e < 9; ++e){
        smd[(ty*8 + tx)*9 + e] = topd0[e];
        smi[(ty*8 + tx)*9 + e] = topi0[e];
    }
    __syncthreads();
    if (tid < 32){
        float md[9]; int mid[9];
        #pragma unroll
        for (int e = 0; e < 9; ++e){ md[e] = FINF; mid[e] = 0x7FFFFFFF; }
        for (int t = 0; t < 8; ++t){
            #pragma unroll
            for (int e = 0; e < 9; ++e)
                ins9(md, mid, smd[(tid*8 + t)*9 + e], smi[(tid*8 + t)*9 + e]);
        }
        size_t po = ((size_t)bid*64 + tid)*9;
        #pragma unroll
        for (int e = 0; e < 9; ++e){ PD[po + e] = md[e]; PI[po + e] = mid[e]; }
    }

    // rows 32..63 (i = i0 + 32 + ty)
    __syncthreads();
    #pragma unroll
    for (int e = 0; e < 9; ++e){
        smd[(ty*8 + tx)*9 + e] = topd1[e];
        smi[(ty*8 + tx)*9 + e] = topi1[e];
    }
    __syncthreads();
    if (tid < 32){
        float md[9]; int mid[9];
        #pragma unroll
        for (int e = 0; e < 9; ++e){ md[e] = FINF; mid[e] = 0x7FFFFFFF; }
        for (int t = 0; t < 8; ++t){
            #pragma unroll
            for (int e = 0; e < 9; ++e)
                ins9(md, mid, smd[(tid*8 + t)*9 + e], smi[(tid*8 + t)*9 + e]);
        }
        size_t po = ((size_t)bid*64 + 32 + tid)*9;
        #pragma unroll
        for (int e = 0; e < 9; ++e){ PD[po + e] = md[e]; PI[po + e] = mid[e]; }
    }
}

// ---------------------------------------------------------------------------
// Merge SPLIT partial top-9 lists per row, then gather max-message.
// Block = 16 rows; msg written to H cols [192,384).
// PD/PI layout: partial-block bid = (sp*NBLK + itile)*8 + b, 64 rows each.
// ---------------------------------------------------------------------------
__global__ __launch_bounds__(256) void merge_msg_kernel(
    const float* __restrict__ H, const float* __restrict__ PD, const int* __restrict__ PI,
    float* __restrict__ Hout)
{
    __shared__ int fidx[16*9];
    const int tid = threadIdx.x;
    const int bid = blockIdx.x;
    const int b  = bid / 196;
    const int i0 = (bid % 196) * 16;
    const int base = b * NPIX;

    if (tid < 16){
        int i = i0 + tid;
        int itile = i >> 6, rl = i & 63;
        float md[9]; int mid[9];
        #pragma unroll
        for (int e = 0; e < 9; ++e){ md[e] = FINF; mid[e] = 0x7FFFFFFF; }
        for (int sp = 0; sp < SPLIT; ++sp){
            size_t po = ((size_t)((sp*NBLK + itile)*8 + b)*64 + rl)*9;
            #pragma unroll
            for (int e = 0; e < 9; ++e) ins9(md, mid, PD[po + e], PI[po + e]);
        }
        #pragma unroll
        for (int e = 0; e < 9; ++e) fidx[tid*9 + e] = mid[e];
    }
    __syncthreads();

    int rl = tid >> 4, part = tid & 15;       // 16 rows x 16 col-parts (12 cols each)
    int i = i0 + rl;
    int nbr[9];
    #pragma unroll
    for (int e = 0; e < 9; ++e) nbr[e] = fidx[rl*9 + e];
    const float* pi = H + (size_t)(base + i)*384 + part*12;
    float* po = Hout + (size_t)(base + i)*384 + 192 + part*12;
    #pragma unroll
    for (int q = 0; q < 3; ++q){
        float4 mv = make_float4(-FINF, -FINF, -FINF, -FINF);
        #pragma unroll
        for (int e = 0; e < 9; ++e){
            float4 v = *(const float4*)&H[(size_t)(base + nbr[e])*384 + part*12 + q*4];
            mv.x = fmaxf(mv.x, v.x); mv.y = fmaxf(mv.y, v.y);
            mv.z = fmaxf(mv.z, v.z); mv.w = fmaxf(mv.w, v.w);
        }
        float4 xi = *(const float4*)&pi[q*4];
        *(float4*)&po[q*4] = make_float4(mv.x - xi.x, mv.y - xi.y, mv.z - xi.z, mv.w - xi.w);
    }
}

extern "C" void kernel_launch(void* const* d_in, const int* in_sizes, int n_in,
                              void* d_out, int out_size, void* d_ws, size_t ws_size,
                              hipStream_t stream)
{
    const float* x  = (const float*)d_in[0];
    const float* W1 = (const float*)d_in[1];
    const float* b1 = (const float*)d_in[2];
    const float* s1 = (const float*)d_in[3];
    const float* W2 = (const float*)d_in[4];
    const float* b2 = (const float*)d_in[5];
    const float* s2 = (const float*)d_in[6];
    const float* Wg = (const float*)d_in[7];
    const float* bg = (const float*)d_in[8];
    const float* sg = (const float*)d_in[9];
    const float* W3 = (const float*)d_in[10];
    const float* b3 = (const float*)d_in[11];
    const float* s3 = (const float*)d_in[12];
    const float* W4 = (const float*)d_in[13];
    const float* b4 = (const float*)d_in[14];
    const float* s4 = (const float*)d_in[15];

    float* H  = (float*)d_ws;                       // [25088][384]: xn1 | msg
    float* T1 = H  + (size_t)25088*384;             // LL1 out (dead before partials reuse); later LL3 out
    float* X2 = T1 + (size_t)25088*192;             // graph-conv out (xn2)
    float* SQ = X2 + (size_t)25088*192;             // row sq-norms
    float* PD = T1;                                 // partial dists  (GRID_KNN*64*9 = 1.81M floats)
    int*   PI = (int*)(T1 + (size_t)GRID_KNN*64*9); // partial indices (1.81M ints)
    float* out = (float*)d_out;

    // ffn_lorentz #1
    ll_kernel<192, true , false, false, false><<<GRID_LL, 256, 0, stream>>>(x, 0,   W1, b1, s1, nullptr, nullptr, 0, T1, 192);
    ll_kernel<192, false, true , false, false><<<GRID_LL, 256, 0, stream>>>(T1, 192, W2, b2, s2, x,      nullptr, 0, H, 384);
    // graph conv
    sq_kernel<<<NB*NBLK, 256, 0, stream>>>(H, SQ);
    knn_kernel<<<GRID_KNN, 256, 0, stream>>>(H, SQ, PD, PI);
    merge_msg_kernel<<<GRID_MSG, 256, 0, stream>>>(H, PD, PI, H);
    ll_kernel<384, false, false, false, false><<<GRID_LL, 256, 0, stream>>>(H, 384,  Wg, bg, sg, nullptr, nullptr, 0, X2, 192);
    // ffn_lorentz #2 + final shortcut, transposed store
    ll_kernel<192, false, false, false, false><<<GRID_LL, 256, 0, stream>>>(X2, 192, W3, b3, s3, nullptr, nullptr, 0, T1, 192);
    ll_kernel<192, false, true , true , true ><<<GRID_LL, 256, 0, stream>>>(T1, 192, W4, b4, s4, x,      X2, 192, out, 0);
}

// Round 6
// 1479.229 us; speedup vs baseline: 2.0958x; 1.0900x over previous
//
#include <hip/hip_runtime.h>
#include <math.h>

#define NB   8
#define NC   192
#define NPIX 3136
#define NBLK 49            // 3136/64 j-tiles (and i-tiles for knn)
#define SPLIT 8            // j-range splits per i-tile
#define GRID_LL (NB*98)    // 784: M-tile 32
#define GRID_KNN (NB*SPLIT*NBLK)   // 3136
#define GRID_MSG (NB*196)  // 1568: 16 rows per block
#define FINF 3.4e38f

__device__ __forceinline__ float gelu_f(float x){
    float u = 0.7978845608028654f * (x + 0.044715f * x * x * x);
    return 0.5f * x * (1.0f + tanhf(u));
}

// lexicographic (d, idx) less-than
#define LESS9(da,ia,db,ib) ((da) < (db) || ((da) == (db) && (ia) < (ib)))
// conditional swap keeping (a,ia) <= (b,ib); pure ?: selects, register-resident
#define CSW9(a,ia,b,ib) { bool sw_ = LESS9(b,ib,a,ia); float tf_=(a); int ti_=(ia); \
    (a) = sw_? (b) : (a); (ia) = sw_? (ib) : (ia); (b) = sw_? tf_ : (b); (ib) = sw_? ti_ : (ib); }

// top-9 smallest (d, idx), all state in named scalars -> VGPRs (no arrays, no scratch)
struct Top9 {
    float d0,d1,d2,d3,d4,d5,d6,d7,d8;
    int   j0,j1,j2,j3,j4,j5,j6,j7,j8;
    __device__ __forceinline__ void init(){
        d0=d1=d2=d3=d4=d5=d6=d7=d8=FINF;
        j0=j1=j2=j3=j4=j5=j6=j7=j8=0x7FFFFFFF;
    }
    __device__ __forceinline__ void insert(float nd, int ni){
        if (!LESS9(nd, ni, d8, j8)) return;
        d8 = nd; j8 = ni;
        CSW9(d7,j7,d8,j8);
        CSW9(d6,j6,d7,j7);
        CSW9(d5,j5,d6,j6);
        CSW9(d4,j4,d5,j5);
        CSW9(d3,j3,d4,j4);
        CSW9(d2,j2,d3,j3);
        CSW9(d1,j1,d2,j2);
        CSW9(d0,j0,d1,j1);
    }
};

// ---------------------------------------------------------------------------
// Fused GEMM + lorentz_linear. Tile 32 rows x 192 cols, 256 thr:
// tx (0..15) covers 12 cols each, ty (0..15) covers 2 rows each.
// ---------------------------------------------------------------------------
template<int K, bool IN_X, bool ADD_X, bool ADD_RM, bool OUT_T>
__global__ __launch_bounds__(256, 4) void ll_kernel(
    const float* __restrict__ Ain, int in_stride,
    const float* __restrict__ Wt,     // [NC, K] row-major
    const float* __restrict__ bias,   // [NC]
    const float* __restrict__ sptr,   // scalar log_scale
    const float* __restrict__ Xres,   // x (B,C,N) residual, if ADD_X
    const float* __restrict__ Rrm, int r_stride,  // row-major residual, if ADD_RM
    float* __restrict__ Out, int out_stride)
{
    __shared__ float lA[32*36];    // [kk][mm], pad 36
    __shared__ float lW[32*196];   // [kk][nn], pad 196

    const int tid = threadIdx.x;
    const int tx = tid & 15, ty = tid >> 4;
    const int bid = blockIdx.x;
    const int b  = bid / 98;
    const int n0 = (bid % 98) * 32;
    const int row0 = b * NPIX + n0;

    float acc[2][12];
    #pragma unroll
    for (int mi = 0; mi < 2; ++mi)
        #pragma unroll
        for (int j = 0; j < 12; ++j) acc[mi][j] = 0.f;

    for (int kt = 0; kt < K/32; ++kt){
        // ---- stage A (gelu applied here): 32k x 32m ----
        if (IN_X){
            int kk = tid >> 3;
            int m4 = (tid & 7) * 4;
            float4 v = *(const float4*)&Ain[(size_t)(b*NC + kt*32 + kk)*NPIX + n0 + m4];
            v.x = gelu_f(v.x); v.y = gelu_f(v.y); v.z = gelu_f(v.z); v.w = gelu_f(v.w);
            *(float4*)&lA[kk*36 + m4] = v;
        } else {
            int mm = tid >> 3;
            int k4 = (tid & 7) * 4;
            float4 v = *(const float4*)&Ain[(size_t)(row0 + mm)*in_stride + kt*32 + k4];
            v.x = gelu_f(v.x); v.y = gelu_f(v.y); v.z = gelu_f(v.z); v.w = gelu_f(v.w);
            lA[(k4+0)*36 + mm] = v.x; lA[(k4+1)*36 + mm] = v.y;
            lA[(k4+2)*36 + mm] = v.z; lA[(k4+3)*36 + mm] = v.w;
        }
        // ---- stage W (transposed): 32k x 192n ----
        #pragma unroll
        for (int r = 0; r < 6; ++r){
            int e  = tid + r*256;
            int nn = e >> 3;
            int k4 = (e & 7) * 4;
            float4 v = *(const float4*)&Wt[nn*K + kt*32 + k4];
            lW[(k4+0)*196 + nn] = v.x; lW[(k4+1)*196 + nn] = v.y;
            lW[(k4+2)*196 + nn] = v.z; lW[(k4+3)*196 + nn] = v.w;
        }
        __syncthreads();
        #pragma unroll
        for (int kk = 0; kk < 32; ++kk){
            float2 a2 = *(const float2*)&lA[kk*36 + ty*2];
            float4 w0 = *(const float4*)&lW[kk*196 + tx*12];
            float4 w1 = *(const float4*)&lW[kk*196 + tx*12 + 4];
            float4 w2 = *(const float4*)&lW[kk*196 + tx*12 + 8];
            float aw[2]  = {a2.x, a2.y};
            float wv[12] = {w0.x,w0.y,w0.z,w0.w, w1.x,w1.y,w1.z,w1.w, w2.x,w2.y,w2.z,w2.w};
            #pragma unroll
            for (int mi = 0; mi < 2; ++mi)
                #pragma unroll
                for (int j = 0; j < 12; ++j)
                    acc[mi][j] = fmaf(aw[mi], wv[j], acc[mi][j]);
        }
        __syncthreads();
    }

    // ---- lorentz epilogue ----
    const int lane = tid & 63;
    float es = expf(sptr[0]);
    float bv[12];
    #pragma unroll
    for (int q = 0; q < 3; ++q){
        float4 t4 = *(const float4*)&bias[tx*12 + q*4];
        bv[q*4+0] = t4.x; bv[q*4+1] = t4.y; bv[q*4+2] = t4.z; bv[q*4+3] = t4.w;
    }
    #pragma unroll
    for (int mi = 0; mi < 2; ++mi){
        float part = 0.f;
        #pragma unroll
        for (int j = 0; j < 12; ++j){
            float y = acc[mi][j] + bv[j];
            acc[mi][j] = y;
            if (!(tx == 0 && j == 0)) part += y * y;   // exclude global col 0
        }
        #pragma unroll
        for (int m = 1; m < 16; m <<= 1) part += __shfl_xor(part, m, 64);
        float y0   = __shfl(acc[mi][0], lane & 48, 64);   // col-0 value of this row
        float tval = es / (1.f + expf(-y0)) + 1.1f;
        float denom = fmaxf(part, 1e-8f);
        float sca  = (tval*tval - 1.f) / denom;
        float sqs  = sqrtf(sca);
        #pragma unroll
        for (int j = 0; j < 12; ++j){
            float o = acc[mi][j] * sqs;
            if (tx == 0 && j == 0) o = tval;
            acc[mi][j] = o;
        }
    }
    if (ADD_X){
        #pragma unroll
        for (int j = 0; j < 12; ++j){
            int c = tx*12 + j;
            float2 xv = *(const float2*)&Xres[(size_t)(b*NC + c)*NPIX + n0 + ty*2];
            acc[0][j] += xv.x; acc[1][j] += xv.y;
        }
    }
    if (ADD_RM){
        #pragma unroll
        for (int mi = 0; mi < 2; ++mi){
            #pragma unroll
            for (int q = 0; q < 3; ++q){
                float4 rv = *(const float4*)&Rrm[(size_t)(row0 + ty*2 + mi)*r_stride + tx*12 + q*4];
                acc[mi][q*4+0] += rv.x; acc[mi][q*4+1] += rv.y;
                acc[mi][q*4+2] += rv.z; acc[mi][q*4+3] += rv.w;
            }
        }
    }
    if (OUT_T){
        #pragma unroll
        for (int j = 0; j < 12; ++j){
            int c = tx*12 + j;
            *(float2*)&Out[(size_t)(b*NC + c)*NPIX + n0 + ty*2] = make_float2(acc[0][j], acc[1][j]);
        }
    } else {
        #pragma unroll
        for (int mi = 0; mi < 2; ++mi){
            #pragma unroll
            for (int q = 0; q < 3; ++q){
                float4 o = make_float4(acc[mi][q*4+0], acc[mi][q*4+1], acc[mi][q*4+2], acc[mi][q*4+3]);
                *(float4*)&Out[(size_t)(row0 + ty*2 + mi)*out_stride + tx*12 + q*4] = o;
            }
        }
    }
}

// ---------------------------------------------------------------------------
// Row squared-norms of xn1 (stored in H cols [0,192), stride 384)
// ---------------------------------------------------------------------------
__global__ __launch_bounds__(256) void sq_kernel(const float* __restrict__ H, float* __restrict__ SQ){
    int tid = threadIdx.x;
    int row = blockIdx.x * 64 + (tid >> 2);
    const float* p = H + (size_t)row*384 + (tid & 3)*48;
    float s = 0.f;
    #pragma unroll
    for (int q = 0; q < 12; ++q){
        float4 v = *(const float4*)&p[q*4];
        s = fmaf(v.x, v.x, fmaf(v.y, v.y, fmaf(v.z, v.z, fmaf(v.w, v.w, s))));
    }
    s += __shfl_xor(s, 1, 64);
    s += __shfl_xor(s, 2, 64);
    if ((tid & 3) == 0) SQ[row] = s;
}

// XOR-swizzled LDS float index: row-stride 64, quad permuted by (row&15)
__device__ __forceinline__ int swz(int r, int cq){
    return r*64 + ((cq ^ (r & 15)) << 2);
}

// ---------------------------------------------------------------------------
// Partial kNN(top-9). Block = 64 i-rows x (subset of j-tiles). 256 thr =
// 32 ty (2 i-rows: ty, ty+32) x 8 tx (8 j: tx+8*jj). c chunked x64.
// bid = (sp*NBLK + itile)*8 + b  -> XCD round-robin keeps one batch per XCD.
// Writes per-row top-9 (d,idx) partials; merged by merge_msg_kernel.
// ---------------------------------------------------------------------------
__global__ __launch_bounds__(256, 4) void knn_kernel(
    const float* __restrict__ H, const float* __restrict__ SQ,
    float* __restrict__ PD, int* __restrict__ PI)
{
    __shared__ float lXi[4096];
    __shared__ float lXj[4096];
    __shared__ float lSq[64];

    const int tid = threadIdx.x;
    const int tx = tid & 7, ty = tid >> 3;
    const int bid = blockIdx.x;
    const int b   = bid & 7;                // XCD-aligned batch
    const int t2  = bid >> 3;               // sp*NBLK + itile
    const int itile = t2 % NBLK;
    const int sp  = t2 / NBLK;
    const int i0  = itile * 64;
    const int base = b * NPIX;
    const int jt0 = (sp * NBLK) / SPLIT;
    const int jt1 = ((sp + 1) * NBLK) / SPLIT;

    Top9 t0, t1;
    t0.init(); t1.init();

    for (int jt = jt0; jt < jt1; ++jt){
        int j0 = jt * 64;
        float dac[2][8];
        #pragma unroll
        for (int mi = 0; mi < 2; ++mi)
            #pragma unroll
            for (int jj = 0; jj < 8; ++jj) dac[mi][jj] = 0.f;

        for (int ch = 0; ch < 3; ++ch){
            __syncthreads();
            #pragma unroll
            for (int r = 0; r < 4; ++r){
                int e  = tid + r*256;          // 1024 float4 = 64 rows x 16 quads
                int rw = e >> 4;
                int q  = e & 15;
                float4 vi = *(const float4*)&H[(size_t)(base + i0 + rw)*384 + ch*64 + q*4];
                *(float4*)&lXi[swz(rw, q)] = vi;
                float4 vj = *(const float4*)&H[(size_t)(base + j0 + rw)*384 + ch*64 + q*4];
                *(float4*)&lXj[swz(rw, q)] = vj;
            }
            if (ch == 0 && tid < 16){
                float4 sv = *(const float4*)&SQ[base + j0 + tid*4];
                *(float4*)&lSq[tid*4] = sv;
            }
            __syncthreads();
            #pragma unroll
            for (int cq = 0; cq < 16; ++cq){
                float4 a0 = *(const float4*)&lXi[swz(ty,      cq)];
                float4 a1 = *(const float4*)&lXi[swz(ty + 32, cq)];
                #pragma unroll
                for (int jj = 0; jj < 8; ++jj){
                    float4 w = *(const float4*)&lXj[swz(tx + 8*jj, cq)];
                    dac[0][jj] = fmaf(a0.x, w.x, fmaf(a0.y, w.y, fmaf(a0.z, w.z, fmaf(a0.w, w.w, dac[0][jj]))));
                    dac[1][jj] = fmaf(a1.x, w.x, fmaf(a1.y, w.y, fmaf(a1.z, w.z, fmaf(a1.w, w.w, dac[1][jj]))));
                }
            }
        }
        #pragma unroll
        for (int jj = 0; jj < 8; ++jj){
            int j = j0 + tx + 8*jj;
            float sqj = lSq[tx + 8*jj];
            float dd0 = fmaf(-2.f, dac[0][jj], sqj);
            t0.insert(dd0, j);
            float dd1 = fmaf(-2.f, dac[1][jj], sqj);
            t1.insert(dd1, j);
        }
    }

    // ---- merge 8 tx-stripes per row; two statically-separate halves ----
    float* smd = lXi;
    int*   smi = (int*)lXj;

    // rows 0..31 (i = i0 + ty)
    __syncthreads();
    {
        int s9 = (ty*8 + tx)*9;
        smd[s9+0]=t0.d0; smd[s9+1]=t0.d1; smd[s9+2]=t0.d2; smd[s9+3]=t0.d3; smd[s9+4]=t0.d4;
        smd[s9+5]=t0.d5; smd[s9+6]=t0.d6; smd[s9+7]=t0.d7; smd[s9+8]=t0.d8;
        smi[s9+0]=t0.j0; smi[s9+1]=t0.j1; smi[s9+2]=t0.j2; smi[s9+3]=t0.j3; smi[s9+4]=t0.j4;
        smi[s9+5]=t0.j5; smi[s9+6]=t0.j6; smi[s9+7]=t0.j7; smi[s9+8]=t0.j8;
    }
    __syncthreads();
    if (tid < 32){
        Top9 m; m.init();
        for (int t = 0; t < 8; ++t){
            int s9 = (tid*8 + t)*9;
            #pragma unroll
            for (int e = 0; e < 9; ++e) m.insert(smd[s9+e], smi[s9+e]);
        }
        size_t po = ((size_t)bid*64 + tid)*9;
        PD[po+0]=m.d0; PD[po+1]=m.d1; PD[po+2]=m.d2; PD[po+3]=m.d3; PD[po+4]=m.d4;
        PD[po+5]=m.d5; PD[po+6]=m.d6; PD[po+7]=m.d7; PD[po+8]=m.d8;
        PI[po+0]=m.j0; PI[po+1]=m.j1; PI[po+2]=m.j2; PI[po+3]=m.j3; PI[po+4]=m.j4;
        PI[po+5]=m.j5; PI[po+6]=m.j6; PI[po+7]=m.j7; PI[po+8]=m.j8;
    }

    // rows 32..63 (i = i0 + 32 + ty)
    __syncthreads();
    {
        int s9 = (ty*8 + tx)*9;
        smd[s9+0]=t1.d0; smd[s9+1]=t1.d1; smd[s9+2]=t1.d2; smd[s9+3]=t1.d3; smd[s9+4]=t1.d4;
        smd[s9+5]=t1.d5; smd[s9+6]=t1.d6; smd[s9+7]=t1.d7; smd[s9+8]=t1.d8;
        smi[s9+0]=t1.j0; smi[s9+1]=t1.j1; smi[s9+2]=t1.j2; smi[s9+3]=t1.j3; smi[s9+4]=t1.j4;
        smi[s9+5]=t1.j5; smi[s9+6]=t1.j6; smi[s9+7]=t1.j7; smi[s9+8]=t1.j8;
    }
    __syncthreads();
    if (tid < 32){
        Top9 m; m.init();
        for (int t = 0; t < 8; ++t){
            int s9 = (tid*8 + t)*9;
            #pragma unroll
            for (int e = 0; e < 9; ++e) m.insert(smd[s9+e], smi[s9+e]);
        }
        size_t po = ((size_t)bid*64 + 32 + tid)*9;
        PD[po+0]=m.d0; PD[po+1]=m.d1; PD[po+2]=m.d2; PD[po+3]=m.d3; PD[po+4]=m.d4;
        PD[po+5]=m.d5; PD[po+6]=m.d6; PD[po+7]=m.d7; PD[po+8]=m.d8;
        PI[po+0]=m.j0; PI[po+1]=m.j1; PI[po+2]=m.j2; PI[po+3]=m.j3; PI[po+4]=m.j4;
        PI[po+5]=m.j5; PI[po+6]=m.j6; PI[po+7]=m.j7; PI[po+8]=m.j8;
    }
}

// ---------------------------------------------------------------------------
// Merge SPLIT partial top-9 lists per row, then gather max-message.
// Block = 16 rows; msg written to H cols [192,384).
// PD/PI layout: partial-block bid = (sp*NBLK + itile)*8 + b, 64 rows each.
// ---------------------------------------------------------------------------
__global__ __launch_bounds__(256) void merge_msg_kernel(
    const float* __restrict__ H, const float* __restrict__ PD, const int* __restrict__ PI,
    float* __restrict__ Hout)
{
    __shared__ int fidx[16*9];
    const int tid = threadIdx.x;
    const int bid = blockIdx.x;
    const int b  = bid / 196;
    const int i0 = (bid % 196) * 16;
    const int base = b * NPIX;

    if (tid < 16){
        int i = i0 + tid;
        int itile = i >> 6, rl = i & 63;
        Top9 m; m.init();
        for (int sp = 0; sp < SPLIT; ++sp){
            size_t po = ((size_t)((sp*NBLK + itile)*8 + b)*64 + rl)*9;
            #pragma unroll
            for (int e = 0; e < 9; ++e) m.insert(PD[po + e], PI[po + e]);
        }
        fidx[tid*9+0]=m.j0; fidx[tid*9+1]=m.j1; fidx[tid*9+2]=m.j2; fidx[tid*9+3]=m.j3;
        fidx[tid*9+4]=m.j4; fidx[tid*9+5]=m.j5; fidx[tid*9+6]=m.j6; fidx[tid*9+7]=m.j7;
        fidx[tid*9+8]=m.j8;
    }
    __syncthreads();

    int rl = tid >> 4, part = tid & 15;       // 16 rows x 16 col-parts (12 cols each)
    int i = i0 + rl;
    int nbr[9];
    #pragma unroll
    for (int e = 0; e < 9; ++e) nbr[e] = fidx[rl*9 + e];
    const float* pi = H + (size_t)(base + i)*384 + part*12;
    float* po = Hout + (size_t)(base + i)*384 + 192 + part*12;
    #pragma unroll
    for (int q = 0; q < 3; ++q){
        float4 mv = make_float4(-FINF, -FINF, -FINF, -FINF);
        #pragma unroll
        for (int e = 0; e < 9; ++e){
            float4 v = *(const float4*)&H[(size_t)(base + nbr[e])*384 + part*12 + q*4];
            mv.x = fmaxf(mv.x, v.x); mv.y = fmaxf(mv.y, v.y);
            mv.z = fmaxf(mv.z, v.z); mv.w = fmaxf(mv.w, v.w);
        }
        float4 xi = *(const float4*)&pi[q*4];
        *(float4*)&po[q*4] = make_float4(mv.x - xi.x, mv.y - xi.y, mv.z - xi.z, mv.w - xi.w);
    }
}

extern "C" void kernel_launch(void* const* d_in, const int* in_sizes, int n_in,
                              void* d_out, int out_size, void* d_ws, size_t ws_size,
                              hipStream_t stream)
{
    const float* x  = (const float*)d_in[0];
    const float* W1 = (const float*)d_in[1];
    const float* b1 = (const float*)d_in[2];
    const float* s1 = (const float*)d_in[3];
    const float* W2 = (const float*)d_in[4];
    const float* b2 = (const float*)d_in[5];
    const float* s2 = (const float*)d_in[6];
    const float* Wg = (const float*)d_in[7];
    const float* bg = (const float*)d_in[8];
    const float* sg = (const float*)d_in[9];
    const float* W3 = (const float*)d_in[10];
    const float* b3 = (const float*)d_in[11];
    const float* s3 = (const float*)d_in[12];
    const float* W4 = (const float*)d_in[13];
    const float* b4 = (const float*)d_in[14];
    const float* s4 = (const float*)d_in[15];

    float* H  = (float*)d_ws;                       // [25088][384]: xn1 | msg
    float* T1 = H  + (size_t)25088*384;             // LL1 out (dead before partials reuse); later LL3 out
    float* X2 = T1 + (size_t)25088*192;             // graph-conv out (xn2)
    float* SQ = X2 + (size_t)25088*192;             // row sq-norms
    float* PD = T1;                                 // partial dists  (GRID_KNN*64*9 = 1.81M floats)
    int*   PI = (int*)(T1 + (size_t)GRID_KNN*64*9); // partial indices (1.81M ints)
    float* out = (float*)d_out;

    // ffn_lorentz #1
    ll_kernel<192, true , false, false, false><<<GRID_LL, 256, 0, stream>>>(x, 0,   W1, b1, s1, nullptr, nullptr, 0, T1, 192);
    ll_kernel<192, false, true , false, false><<<GRID_LL, 256, 0, stream>>>(T1, 192, W2, b2, s2, x,      nullptr, 0, H, 384);
    // graph conv
    sq_kernel<<<NB*NBLK, 256, 0, stream>>>(H, SQ);
    knn_kernel<<<GRID_KNN, 256, 0, stream>>>(H, SQ, PD, PI);
    merge_msg_kernel<<<GRID_MSG, 256, 0, stream>>>(H, PD, PI, H);
    ll_kernel<384, false, false, false, false><<<GRID_LL, 256, 0, stream>>>(H, 384,  Wg, bg, sg, nullptr, nullptr, 0, X2, 192);
    // ffn_lorentz #2 + final shortcut, transposed store
    ll_kernel<192, false, false, false, false><<<GRID_LL, 256, 0, stream>>>(X2, 192, W3, b3, s3, nullptr, nullptr, 0, T1, 192);
    ll_kernel<192, false, true , true , true ><<<GRID_LL, 256, 0, stream>>>(T1, 192, W4, b4, s4, x,      X2, 192, out, 0);
}